// Round 16
// baseline (243.636 us; speedup 1.0000x reference)
//
#include <hip/hip_runtime.h>
#include <hip/hip_bf16.h>

typedef __attribute__((ext_vector_type(4))) float f32x4;
typedef __attribute__((ext_vector_type(8))) short bf16x8;

constexpr int NB = 16, NN = 2048, NS = 4, NDIM = 512, NH = 8, NDS = 64;
constexpr float LOG2PI = 1.8378770664093453f;
constexpr float INV_SQRT_DIM = 0.04419417382415922f;  // 1/sqrt(512)

__device__ inline short f2bf(float f) {           // hardware RNE (v_cvt_pk_bf16_f32 pairs)
  __hip_bfloat16 h = __float2bfloat16(f);
  return *reinterpret_cast<short*>(&h);
}
__device__ inline float bf2f(short b) {
  union { unsigned u; float f; } v;
  v.u = ((unsigned)(unsigned short)b) << 16;
  return v.f;
}

__device__ inline void gld16(const void* g, void* l) {
  __builtin_amdgcn_global_load_lds(
      (const __attribute__((address_space(1))) void*)g,
      (__attribute__((address_space(3))) void*)l, 16, 0, 0);
}

// ---------------------------------------------------------------------------
// Merged prep: blocks [0,1024): Wv transpose; [1024,1152): Wk -> bf16;
// [1152,1160): GMM tables + lp2.
// ---------------------------------------------------------------------------
__global__ __launch_bounds__(256) void prep_kernel(
    const float* __restrict__ Wv, float* __restrict__ WvT,
    const float* __restrict__ Wk, short* __restrict__ Wkb,
    const float* __restrict__ Mp, const float* __restrict__ Sp,
    const float* __restrict__ pp, const float* __restrict__ bkp,
    float4* __restrict__ gmm, float* __restrict__ lp2)
{
  const int blk = blockIdx.x;
  const int tid = threadIdx.x;
  if (blk < 1024) {                       // WvT[(h*512+i)*64+d] = Wv[(h*64+d)*512+i]
    const int idx = blk * 256 + tid;      // 0..262143
    const int d = idx & 63;
    const int i = (idx >> 6) & 511;
    const int h = idx >> 15;
    WvT[idx] = Wv[(size_t)(h * 64 + d) * 512 + i];
  } else if (blk < 1152) {                // Wk -> bf16, 8 elems/thread
    const int j = (blk - 1024) * 256 + tid;  // 0..32767
    const float4 a = reinterpret_cast<const float4*>(Wk)[(size_t)j * 2];
    const float4 b = reinterpret_cast<const float4*>(Wk)[(size_t)j * 2 + 1];
    bf16x8 o;
    o[0] = f2bf(a.x); o[1] = f2bf(a.y); o[2] = f2bf(a.z); o[3] = f2bf(a.w);
    o[4] = f2bf(b.x); o[5] = f2bf(b.y); o[6] = f2bf(b.z); o[7] = f2bf(b.w);
    *reinterpret_cast<bf16x8*>(&Wkb[(size_t)j * 8]) = o;
  } else {                                // GMM tables
    const int idx = (blk - 1152) * 256 + tid;  // 0..2047
    const int Jg = idx & 511;
    const float sv = Sp[idx];
    const float sig = log1pf(expf(sv));   // softplus
    float4 o;
    o.x = Mp[idx];
    o.y = (-0.5f * LOG2PI - logf(sig)) * INV_SQRT_DIM;
    o.z = (0.5f / (sig * sig)) * INV_SQRT_DIM;
    o.w = bkp[Jg];
    gmm[idx] = o;
    if (idx < 4) {
      const float p0 = pp[0], p1 = pp[1], p2 = pp[2], p3 = pp[3];
      const float pmx = fmaxf(fmaxf(p0, p1), fmaxf(p2, p3));
      const float lse = pmx + logf(expf(p0 - pmx) + expf(p1 - pmx) +
                                   expf(p2 - pmx) + expf(p3 - pmx));
      lp2[idx] = (pp[idx] - lse) * INV_SQRT_DIM;
    }
  }
}

// ---------------------------------------------------------------------------
// kproj part 1 (fused-cvt form, ct=0): 1024 blocks; reg-stages A from fp32 X,
// converts, writes Xb (each row once), B via gld_lds; heads 0-1 ll.
// ---------------------------------------------------------------------------
__global__ __launch_bounds__(256) void kproj1_kernel(
    const float* __restrict__ X, const short* __restrict__ Wkb,
    const float4* __restrict__ gmm, const float* __restrict__ lp2,
    float* __restrict__ ll_ws, short* __restrict__ Xb)
{
  __shared__ short As[2][128 * 64];
  __shared__ short Bs[2][128 * 64];

  const int bid0 = blockIdx.x;
  const int mt = (bid0 & 7) * 128 + (bid0 >> 3);
  const int m0 = mt * 128;
  const int c0 = 0;                        // ct = 0 -> heads 0,1

  const int t = threadIdx.x;
  const int l = t & 63;
  const int w = t >> 6;
  const int wr = w >> 1, wc = w & 1;
  const int lg = l >> 4, lr = l & 15;

  f32x4 acc[4][4] = {};

  const int g8 = (l & 7) ^ (l >> 3);
  const size_t gba = (size_t)(c0 + w * 32 + (l >> 3)) * NDIM + g8 * 8;
  const int dB = (w * 32) * 64;
  auto stageB = [&](int buf, int ts) {
    const int k0 = ts << 6;
    #pragma unroll
    for (int q = 0; q < 4; ++q)
      gld16(&Wkb[gba + (size_t)(q * 8) * NDIM + k0], (char*)&Bs[buf][dB + q * 8 * 64]);
  };

  float4 rA[4][2];
  auto issueA = [&](int ts) {
    const int k0 = ts << 6;
    #pragma unroll
    for (int u = 0; u < 4; ++u) {
      const int bc = u * 256 + t;
      const int row = bc >> 3, c = bc & 7;
      const float* src = &X[(size_t)(m0 + row) * NDIM + k0 + c * 8];
      rA[u][0] = *reinterpret_cast<const float4*>(src);
      rA[u][1] = *reinterpret_cast<const float4*>(src + 4);
    }
  };
  auto cvtWriteA = [&](int buf, int ts) {
    const int k0 = ts << 6;
    #pragma unroll
    for (int u = 0; u < 4; ++u) {
      const int bc = u * 256 + t;
      const int row = bc >> 3, c = bc & 7;
      bf16x8 o;
      o[0] = f2bf(rA[u][0].x); o[1] = f2bf(rA[u][0].y);
      o[2] = f2bf(rA[u][0].z); o[3] = f2bf(rA[u][0].w);
      o[4] = f2bf(rA[u][1].x); o[5] = f2bf(rA[u][1].y);
      o[6] = f2bf(rA[u][1].z); o[7] = f2bf(rA[u][1].w);
      *reinterpret_cast<bf16x8*>(
          (char*)&As[buf][0] + row * 128 + ((c ^ (row & 7)) << 4)) = o;
      *reinterpret_cast<bf16x8*>(&Xb[(size_t)(m0 + row) * NDIM + k0 + c * 8]) = o;
    }
  };

  auto compute = [&](int buf) {
    #pragma unroll
    for (int kk = 0; kk < 64; kk += 32) {
      bf16x8 a[4], b[4];
      #pragma unroll
      for (int i = 0; i < 4; ++i) {
        const int r = wr * 64 + i * 16 + lr;
        const int byte = r * 128 + ((((kk >> 3) + lg) ^ (lr & 7)) << 4);
        a[i] = *reinterpret_cast<const bf16x8*>((const char*)&As[buf][0] + byte);
      }
      #pragma unroll
      for (int j = 0; j < 4; ++j) {
        const int r = wc * 64 + j * 16 + lr;
        const int byte = r * 128 + ((((kk >> 3) + lg) ^ (lr & 7)) << 4);
        b[j] = *reinterpret_cast<const bf16x8*>((const char*)&Bs[buf][0] + byte);
      }
      #pragma unroll
      for (int i = 0; i < 4; ++i) {
        #pragma unroll
        for (int j = 0; j < 4; ++j)
          acc[i][j] = __builtin_amdgcn_mfma_f32_16x16x32_bf16(a[i], b[j], acc[i][j], 0, 0, 0);
      }
    }
  };

  issueA(0);
  cvtWriteA(0, 0);
  stageB(0, 0);
  issueA(1);
  asm volatile("s_waitcnt vmcnt(8)" ::: "memory");
  asm volatile("s_waitcnt lgkmcnt(0)" ::: "memory");
  __builtin_amdgcn_s_barrier();
  __builtin_amdgcn_sched_barrier(0);
  for (int ts = 0; ts < 7; ++ts) {
    cvtWriteA((ts + 1) & 1, ts + 1);
    stageB((ts + 1) & 1, ts + 1);
    if (ts < 6) issueA(ts + 2);
    asm volatile("s_waitcnt lgkmcnt(0)" ::: "memory");
    __builtin_amdgcn_s_barrier();
    compute(ts & 1);
    __builtin_amdgcn_s_barrier();
  }
  asm volatile("s_waitcnt vmcnt(0)" ::: "memory");
  __builtin_amdgcn_s_barrier();
  compute(1);
  __builtin_amdgcn_sched_barrier(0);

  const float l0 = lp2[0], l1 = lp2[1], l2 = lp2[2], l3 = lp2[3];
  const float lpv[4] = {l0, l1, l2, l3};

  float part[4][4];
  #pragma unroll
  for (int i = 0; i < 4; ++i)
    #pragma unroll
    for (int e = 0; e < 4; ++e) part[i][e] = 0.f;

  #pragma unroll
  for (int j = 0; j < 4; ++j) {
    const int Jg = c0 + wc * 64 + j * 16 + lr;
    #pragma unroll
    for (int e = 0; e < 4; ++e) {
      const float4 gw = gmm[e * NDIM + Jg];
      #pragma unroll
      for (int i = 0; i < 4; ++i) {
        const float kv = acc[i][j][e] + gw.w;
        const float d = kv - gw.x;
        part[i][e] += gw.y - d * d * gw.z;
      }
    }
  }
  #pragma unroll
  for (int off = 1; off < 16; off <<= 1) {
    #pragma unroll
    for (int i = 0; i < 4; ++i)
      #pragma unroll
      for (int e = 0; e < 4; ++e)
        part[i][e] += __shfl_xor(part[i][e], off, 64);
  }
  if (lr == 0) {
    const int h = wc;                        // ct = 0
    #pragma unroll
    for (int i = 0; i < 4; ++i) {
      #pragma unroll
      for (int e = 0; e < 4; ++e) {
        const int R = m0 + wr * 64 + i * 16 + 4 * lg + e;
        const int bn = R >> 2;
        const int bb = bn >> 11;
        const int nn = bn & (NN - 1);
        ll_ws[((size_t)((bb * NS + e) * NH + h)) * NN + nn] = part[i][e] + lpv[e];
      }
    }
  }
}

// ---------------------------------------------------------------------------
// kproj part 2 (gld_lds form, ct = 1..3): 3072 blocks. Heads 2-7.
// ---------------------------------------------------------------------------
__global__ __launch_bounds__(256) void kproj2_kernel(
    const short* __restrict__ Xb, const short* __restrict__ Wkb,
    const float4* __restrict__ gmm, const float* __restrict__ lp2,
    float* __restrict__ ll_ws)
{
  __shared__ short As[2][128 * 64];
  __shared__ short Bs[2][128 * 64];

  const int bid0 = blockIdx.x;
  const int xcd = bid0 & 7;
  const int q = bid0 >> 3;                 // 0..383
  const int mt = xcd * 128 + q / 3;
  const int ct = 1 + q % 3;                // 1..3
  const int m0 = mt * 128;
  const int c0 = ct * 128;

  const int t = threadIdx.x;
  const int l = t & 63;
  const int w = t >> 6;
  const int wr = w >> 1, wc = w & 1;
  const int lg = l >> 4, lr = l & 15;

  f32x4 acc[4][4] = {};

  const int g8 = (l & 7) ^ (l >> 3);
  const size_t gxa = (size_t)(m0 + w * 32 + (l >> 3)) * NDIM + g8 * 8;
  const size_t gba = (size_t)(c0 + w * 32 + (l >> 3)) * NDIM + g8 * 8;
  const int dA = (w * 32) * 64;

  auto stage = [&](int buf, int ts) {
    const int k0 = ts << 6;
    #pragma unroll
    for (int qq = 0; qq < 4; ++qq) {
      const size_t so = (size_t)(qq * 8) * NDIM + k0;
      const int dd = dA + (qq * 8) * 64;
      gld16(&Xb[gxa + so],  (char*)&As[buf][dd]);
      gld16(&Wkb[gba + so], (char*)&Bs[buf][dd]);
    }
  };

  auto compute = [&](int buf) {
    #pragma unroll
    for (int kk = 0; kk < 64; kk += 32) {
      bf16x8 a[4], b[4];
      #pragma unroll
      for (int i = 0; i < 4; ++i) {
        const int r = wr * 64 + i * 16 + lr;
        const int byte = r * 128 + ((((kk >> 3) + lg) ^ (lr & 7)) << 4);
        a[i] = *reinterpret_cast<const bf16x8*>((const char*)&As[buf][0] + byte);
      }
      #pragma unroll
      for (int j = 0; j < 4; ++j) {
        const int r = wc * 64 + j * 16 + lr;
        const int byte = r * 128 + ((((kk >> 3) + lg) ^ (lr & 7)) << 4);
        b[j] = *reinterpret_cast<const bf16x8*>((const char*)&Bs[buf][0] + byte);
      }
      #pragma unroll
      for (int i = 0; i < 4; ++i) {
        #pragma unroll
        for (int j = 0; j < 4; ++j)
          acc[i][j] = __builtin_amdgcn_mfma_f32_16x16x32_bf16(a[i], b[j], acc[i][j], 0, 0, 0);
      }
    }
  };

  stage(0, 0);
  __builtin_amdgcn_sched_barrier(0);
  for (int ts = 0; ts < 7; ++ts) {
    stage((ts + 1) & 1, ts + 1);
    asm volatile("s_waitcnt vmcnt(8)" ::: "memory");
    __builtin_amdgcn_s_barrier();
    compute(ts & 1);
    __builtin_amdgcn_s_barrier();
  }
  asm volatile("s_waitcnt vmcnt(0)" ::: "memory");
  __builtin_amdgcn_s_barrier();
  compute(1);
  __builtin_amdgcn_sched_barrier(0);

  const float l0 = lp2[0], l1 = lp2[1], l2 = lp2[2], l3 = lp2[3];
  const float lpv[4] = {l0, l1, l2, l3};

  float part[4][4];
  #pragma unroll
  for (int i = 0; i < 4; ++i)
    #pragma unroll
    for (int e = 0; e < 4; ++e) part[i][e] = 0.f;

  #pragma unroll
  for (int j = 0; j < 4; ++j) {
    const int Jg = c0 + wc * 64 + j * 16 + lr;
    #pragma unroll
    for (int e = 0; e < 4; ++e) {
      const float4 gw = gmm[e * NDIM + Jg];
      #pragma unroll
      for (int i = 0; i < 4; ++i) {
        const float kv = acc[i][j][e] + gw.w;
        const float d = kv - gw.x;
        part[i][e] += gw.y - d * d * gw.z;
      }
    }
  }
  #pragma unroll
  for (int off = 1; off < 16; off <<= 1) {
    #pragma unroll
    for (int i = 0; i < 4; ++i)
      #pragma unroll
      for (int e = 0; e < 4; ++e)
        part[i][e] += __shfl_xor(part[i][e], off, 64);
  }
  if (lr == 0) {
    const int h = ct * 2 + wc;               // heads 2..7
    #pragma unroll
    for (int i = 0; i < 4; ++i) {
      #pragma unroll
      for (int e = 0; e < 4; ++e) {
        const int R = m0 + wr * 64 + i * 16 + 4 * lg + e;
        const int bn = R >> 2;
        const int bb = bn >> 11;
        const int nn = bn & (NN - 1);
        ll_ws[((size_t)((bb * NS + e) * NH + h)) * NN + nn] = part[i][e] + lpv[e];
      }
    }
  }
}

// ---------------------------------------------------------------------------
// Y partials with per-chunk online-softmax stats; 16B/lane X reads.
// Block (bs, nq): stats per h over its 256 n's (unchanged); then each WAVE
// owns one n-row per iteration (64 lanes x bf16x8 = full 1KB row), lane l
// accumulates d = l*8..l*8+7 for all 8 heads; 4-wave LDS tree-reduce per h.
// ---------------------------------------------------------------------------
__global__ __launch_bounds__(256) void y_kernel(
    const float* __restrict__ ll_ws, const short* __restrict__ Xb,
    float* __restrict__ Yp, float2* __restrict__ msws)
{
  __shared__ float wT[256][8];
  __shared__ float redm[8][4];
  __shared__ float reds[8][4];
  __shared__ float red[4][8][64];      // [wave][j][l]
  const int blk = blockIdx.x;
  const int bs = blk & 63;             // b*4+s
  const int nq = blk >> 6;             // 0..7
  const int b = bs >> 2, s = bs & 3;
  const int g0 = bs * 8;
  const int t = threadIdx.x;
  const int w = t >> 6, l = t & 63;

  float lv[8];
  #pragma unroll
  for (int h = 0; h < 8; ++h) {
    lv[h] = ll_ws[(size_t)(g0 + h) * NN + nq * 256 + t];
    float mm = lv[h];
    #pragma unroll
    for (int off = 1; off < 64; off <<= 1) mm = fmaxf(mm, __shfl_xor(mm, off, 64));
    if (l == 0) redm[h][w] = mm;
  }
  __syncthreads();
  float mx[8];
  #pragma unroll
  for (int h = 0; h < 8; ++h) {
    mx[h] = fmaxf(fmaxf(redm[h][0], redm[h][1]), fmaxf(redm[h][2], redm[h][3]));
    const float e = expf(lv[h] - mx[h]);
    wT[t][h] = e;
    float ss = e;
    #pragma unroll
    for (int off = 1; off < 64; off <<= 1) ss += __shfl_xor(ss, off, 64);
    if (l == 0) reds[h][w] = ss;
  }
  __syncthreads();
  if (t < 8) {
    const float sum = reds[t][0] + reds[t][1] + reds[t][2] + reds[t][3];
    msws[(size_t)(g0 + t) * 8 + nq] = make_float2(mx[t], sum);
  }

  // X accumulation: wave w covers local n = w*64 .. w*64+63.
  float acc[8][8] = {};                // [h][j], j = d&7 for d = l*8+j
  const size_t rowbase =
      ((size_t)(b * 2048 + nq * 256) * 4 + s) * 512 + (size_t)l * 8;
  #pragma unroll 2
  for (int i = 0; i < 64; ++i) {
    const int nl = w * 64 + i;
    const bf16x8 xv = *reinterpret_cast<const bf16x8*>(
        &Xb[rowbase + (size_t)nl * 2048]);   // row stride 4*512 shorts
    float x[8];
    #pragma unroll
    for (int j = 0; j < 8; ++j) x[j] = bf2f(xv[j]);
    const float4 w0 = *reinterpret_cast<const float4*>(&wT[nl][0]);
    const float4 w1 = *reinterpret_cast<const float4*>(&wT[nl][4]);
    const float wh[8] = {w0.x, w0.y, w0.z, w0.w, w1.x, w1.y, w1.z, w1.w};
    #pragma unroll
    for (int h = 0; h < 8; ++h)
      #pragma unroll
      for (int j = 0; j < 8; ++j) acc[h][j] += wh[h] * x[j];
  }

  // reduce across waves, head by head; output d = l*8 + j.
  #pragma unroll 1
  for (int h = 0; h < 8; ++h) {
    __syncthreads();                    // red free (prev h's readers done)
    #pragma unroll
    for (int j = 0; j < 8; ++j) red[w][j][l] = acc[h][j];
    __syncthreads();
    float* yp = Yp + ((size_t)((nq * 64 + bs) * 8 + h)) * 512;
    #pragma unroll
    for (int u = 0; u < 2; ++u) {
      const int d = u * 256 + t;
      const int jj = d & 7, ll2 = d >> 3;
      yp[d] = red[0][jj][ll2] + red[1][jj][ll2] + red[2][jj][ll2] + red[3][jj][ll2];
    }
  }
}

// ---------------------------------------------------------------------------
// Pool-project with online-softmax merge.
// ---------------------------------------------------------------------------
__global__ __launch_bounds__(256) void poolproj_kernel(
    const float* __restrict__ Yp, const float2* __restrict__ msws,
    const float* __restrict__ WvT, const float* __restrict__ bvp,
    const float* __restrict__ Mp, float* __restrict__ O0)
{
  __shared__ float ys[512];
  __shared__ float pr[4][64];
  const int g = blockIdx.x;            // (b*4+s)*8+h
  const int bs = g >> 3, h = g & 7;
  const int s = bs & 3;
  const int t = threadIdx.x;

  const float2* msp = msws + (size_t)g * 8;
  float M = -1e30f;
  #pragma unroll
  for (int q = 0; q < 8; ++q) M = fmaxf(M, msp[q].x);
  float cq[8];
  float S = 0.f;
  #pragma unroll
  for (int q = 0; q < 8; ++q) {
    cq[q] = expf(msp[q].x - M);
    S += msp[q].y * cq[q];
  }
  const float rS = 1.f / S;

  float a0 = 0.f, a1 = 0.f;
  #pragma unroll
  for (int q = 0; q < 8; ++q) {
    const float* yp = Yp + ((size_t)((q * 64 + bs) * 8 + h)) * 512;
    const float c = cq[q] * rS;
    a0 += yp[t] * c;
    a1 += yp[t + 256] * c;
  }
  ys[t] = a0; ys[t + 256] = a1;
  __syncthreads();

  const int d = t & 63, p = t >> 6;
  const float* wt = WvT + ((size_t)h * 512 + p * 128) * 64 + d;
  const float* yy = ys + p * 128;
  float acc = 0.f;
  #pragma unroll 4
  for (int i = 0; i < 128; ++i) acc += yy[i] * wt[(size_t)i * 64];
  pr[p][d] = acc;
  __syncthreads();
  if (t < 64) {
    const float tot = pr[0][t] + pr[1][t] + pr[2][t] + pr[3][t];
    O0[(size_t)g * 64 + t] = Mp[s * NDIM + h * NDS + t] + bvp[h * 64 + t] + tot;
  }
}

// ---------------------------------------------------------------------------
// Fused BN1 + MLP.
// ---------------------------------------------------------------------------
__global__ __launch_bounds__(256) void bnmlp_kernel(
    const float* __restrict__ O0, const float* __restrict__ gg,
    const float* __restrict__ bb, const float* __restrict__ Wo,
    const float* __restrict__ bo, float* __restrict__ Zo)
{
  __shared__ float ys[512];
  const int blk = blockIdx.x;
  const int t = threadIdx.x;
  const int r = blk >> 1;              // row 0..63 (b*4+s)
  const int b = r >> 2, s = r & 3;

  #pragma unroll
  for (int u = 0; u < 2; ++u) {
    const int i = u * 256 + t;
    const int f = s * 512 + i;
    float x[NB];
    float m = 0.f;
    #pragma unroll
    for (int bq = 0; bq < NB; ++bq) { x[bq] = O0[bq * 2048 + f]; m += x[bq]; }
    m *= (1.f / NB);
    float v = 0.f;
    #pragma unroll
    for (int bq = 0; bq < NB; ++bq) { const float d = x[bq] - m; v += d * d; }
    v *= (1.f / NB);
    const float inv = rsqrtf(v + 1e-5f) * gg[f];
    ys[i] = (x[b] - m) * inv + bb[f];
  }
  __syncthreads();

  const int j = ((blk & 1) << 8) + t;
  const float4* yv = reinterpret_cast<const float4*>(ys);
  const float4* wrow = reinterpret_cast<const float4*>(Wo + (size_t)j * NDIM);
  float acc = 0.f;
  #pragma unroll 4
  for (int i = 0; i < 128; ++i) {
    const float4 a = yv[i], w = wrow[i];
    acc += a.x * w.x + a.y * w.y + a.z * w.z + a.w * w.w;
  }
  Zo[(size_t)r * 512 + j] = ys[j] + fmaxf(acc + bo[j], 0.f);
}

// ---------------------------------------------------------------------------
// Final BatchNorm1d (training mode, biased var, eps=1e-5) over B=16.
// ---------------------------------------------------------------------------
__global__ __launch_bounds__(256) void bn_kernel(
    const float* __restrict__ Xin, const float* __restrict__ gg,
    const float* __restrict__ bb, float* __restrict__ Yo)
{
  const int f = blockIdx.x * 256 + threadIdx.x;  // 0..2047
  float x[NB];
  float m = 0.f;
  #pragma unroll
  for (int b = 0; b < NB; ++b) { x[b] = Xin[b * (NS * NDIM) + f]; m += x[b]; }
  m *= (1.f / NB);
  float v = 0.f;
  #pragma unroll
  for (int b = 0; b < NB; ++b) { const float d = x[b] - m; v += d * d; }
  v *= (1.f / NB);
  const float inv = rsqrtf(v + 1e-5f) * gg[f];
  const float bf = bb[f];
  #pragma unroll
  for (int b = 0; b < NB; ++b) Yo[b * (NS * NDIM) + f] = (x[b] - m) * inv + bf;
}

extern "C" void kernel_launch(void* const* d_in, const int* in_sizes, int n_in,
                              void* d_out, int out_size, void* d_ws, size_t ws_size,
                              hipStream_t stream) {
  (void)in_sizes; (void)n_in; (void)out_size; (void)ws_size;
  const float* X  = (const float*)d_in[0];
  const float* M  = (const float*)d_in[1];
  const float* S  = (const float*)d_in[2];
  const float* p  = (const float*)d_in[3];
  const float* Wk = (const float*)d_in[4];
  const float* bk = (const float*)d_in[5];
  const float* Wv = (const float*)d_in[6];
  const float* bv = (const float*)d_in[7];
  const float* Wo = (const float*)d_in[8];
  const float* bo = (const float*)d_in[9];
  const float* g0 = (const float*)d_in[10];
  const float* b0 = (const float*)d_in[11];
  const float* g1 = (const float*)d_in[12];
  const float* b1 = (const float*)d_in[13];

  char* ws = (char*)d_ws;
  short* Xb    = (short*)ws;                                    // 128 MiB bf16 X
  float* ll_ws = (float*)(ws + (size_t)134217728);              // 4 MiB logits
  float* Yp    = (float*)(ws + (size_t)138416128);              // 8 MiB partials
  float* O0    = (float*)(ws + (size_t)146804736);              // 128 KiB
  float* Z     = (float*)(ws + (size_t)147066880);              // 128 KiB
  short* Wkb   = (short*)(ws + (size_t)147197952);              // 512 KiB
  float* WvT   = (float*)(ws + (size_t)147722240);              // 1 MiB
  float4* gmm  = (float4*)(ws + (size_t)148770816);             // 32 KiB
  float* lp2   = (float*)(ws + (size_t)148803584);              // 16 B
  float2* msws = (float2*)(ws + (size_t)148803712);             // 32 KiB

  prep_kernel<<<1160, 256, 0, stream>>>(Wv, WvT, Wk, Wkb, M, S, p, bk, gmm, lp2);
  kproj1_kernel<<<1024, 256, 0, stream>>>(X, Wkb, gmm, lp2, ll_ws, Xb);
  kproj2_kernel<<<3072, 256, 0, stream>>>(Xb, Wkb, gmm, lp2, ll_ws);
  y_kernel<<<512, 256, 0, stream>>>(ll_ws, Xb, Yp, msws);
  poolproj_kernel<<<512, 256, 0, stream>>>(Yp, msws, WvT, bv, M, O0);
  bnmlp_kernel<<<128, 256, 0, stream>>>(O0, g0, b0, Wo, bo, Z);
  bn_kernel<<<8, 256, 0, stream>>>(Z, g1, b1, (float*)d_out);
}

// Round 17
// 236.297 us; speedup vs baseline: 1.0311x; 1.0311x over previous
//
#include <hip/hip_runtime.h>
#include <hip/hip_bf16.h>

typedef __attribute__((ext_vector_type(4))) float f32x4;
typedef __attribute__((ext_vector_type(8))) short bf16x8;

constexpr int NB = 16, NN = 2048, NS = 4, NDIM = 512, NH = 8, NDS = 64;
constexpr float LOG2PI = 1.8378770664093453f;
constexpr float INV_SQRT_DIM = 0.04419417382415922f;  // 1/sqrt(512)

__device__ inline short f2bf(float f) {           // hardware RNE (v_cvt_pk_bf16_f32 pairs)
  __hip_bfloat16 h = __float2bfloat16(f);
  return *reinterpret_cast<short*>(&h);
}
__device__ inline float bf2f(short b) {
  union { unsigned u; float f; } v;
  v.u = ((unsigned)(unsigned short)b) << 16;
  return v.f;
}

__device__ inline void gld16(const void* g, void* l) {
  __builtin_amdgcn_global_load_lds(
      (const __attribute__((address_space(1))) void*)g,
      (__attribute__((address_space(3))) void*)l, 16, 0, 0);
}

// ---------------------------------------------------------------------------
// Merged prep: blocks [0,1024): Wv transpose; [1024,1152): Wk -> bf16;
// [1152,1160): GMM tables + lp2.
// ---------------------------------------------------------------------------
__global__ __launch_bounds__(256) void prep_kernel(
    const float* __restrict__ Wv, float* __restrict__ WvT,
    const float* __restrict__ Wk, short* __restrict__ Wkb,
    const float* __restrict__ Mp, const float* __restrict__ Sp,
    const float* __restrict__ pp, const float* __restrict__ bkp,
    float4* __restrict__ gmm, float* __restrict__ lp2)
{
  const int blk = blockIdx.x;
  const int tid = threadIdx.x;
  if (blk < 1024) {                       // WvT[(h*512+i)*64+d] = Wv[(h*64+d)*512+i]
    const int idx = blk * 256 + tid;      // 0..262143
    const int d = idx & 63;
    const int i = (idx >> 6) & 511;
    const int h = idx >> 15;
    WvT[idx] = Wv[(size_t)(h * 64 + d) * 512 + i];
  } else if (blk < 1152) {                // Wk -> bf16, 8 elems/thread
    const int j = (blk - 1024) * 256 + tid;  // 0..32767
    const float4 a = reinterpret_cast<const float4*>(Wk)[(size_t)j * 2];
    const float4 b = reinterpret_cast<const float4*>(Wk)[(size_t)j * 2 + 1];
    bf16x8 o;
    o[0] = f2bf(a.x); o[1] = f2bf(a.y); o[2] = f2bf(a.z); o[3] = f2bf(a.w);
    o[4] = f2bf(b.x); o[5] = f2bf(b.y); o[6] = f2bf(b.z); o[7] = f2bf(b.w);
    *reinterpret_cast<bf16x8*>(&Wkb[(size_t)j * 8]) = o;
  } else {                                // GMM tables
    const int idx = (blk - 1152) * 256 + tid;  // 0..2047
    const int Jg = idx & 511;
    const float sv = Sp[idx];
    const float sig = log1pf(expf(sv));   // softplus
    float4 o;
    o.x = Mp[idx];
    o.y = (-0.5f * LOG2PI - logf(sig)) * INV_SQRT_DIM;
    o.z = (0.5f / (sig * sig)) * INV_SQRT_DIM;
    o.w = bkp[Jg];
    gmm[idx] = o;
    if (idx < 4) {
      const float p0 = pp[0], p1 = pp[1], p2 = pp[2], p3 = pp[3];
      const float pmx = fmaxf(fmaxf(p0, p1), fmaxf(p2, p3));
      const float lse = pmx + logf(expf(p0 - pmx) + expf(p1 - pmx) +
                                   expf(p2 - pmx) + expf(p3 - pmx));
      lp2[idx] = (pp[idx] - lse) * INV_SQRT_DIM;
    }
  }
}

// ---------------------------------------------------------------------------
// kproj part 1 (fused-cvt form, ct=0): 1024 blocks; reg-stages A from fp32 X,
// converts, writes Xb (each row once), B via gld_lds; heads 0-1 ll.
// ---------------------------------------------------------------------------
__global__ __launch_bounds__(256) void kproj1_kernel(
    const float* __restrict__ X, const short* __restrict__ Wkb,
    const float4* __restrict__ gmm, const float* __restrict__ lp2,
    float* __restrict__ ll_ws, short* __restrict__ Xb)
{
  __shared__ short As[2][128 * 64];
  __shared__ short Bs[2][128 * 64];

  const int bid0 = blockIdx.x;
  const int mt = (bid0 & 7) * 128 + (bid0 >> 3);
  const int m0 = mt * 128;
  const int c0 = 0;                        // ct = 0 -> heads 0,1

  const int t = threadIdx.x;
  const int l = t & 63;
  const int w = t >> 6;
  const int wr = w >> 1, wc = w & 1;
  const int lg = l >> 4, lr = l & 15;

  f32x4 acc[4][4] = {};

  const int g8 = (l & 7) ^ (l >> 3);
  const size_t gba = (size_t)(c0 + w * 32 + (l >> 3)) * NDIM + g8 * 8;
  const int dB = (w * 32) * 64;
  auto stageB = [&](int buf, int ts) {
    const int k0 = ts << 6;
    #pragma unroll
    for (int q = 0; q < 4; ++q)
      gld16(&Wkb[gba + (size_t)(q * 8) * NDIM + k0], (char*)&Bs[buf][dB + q * 8 * 64]);
  };

  float4 rA[4][2];
  auto issueA = [&](int ts) {
    const int k0 = ts << 6;
    #pragma unroll
    for (int u = 0; u < 4; ++u) {
      const int bc = u * 256 + t;
      const int row = bc >> 3, c = bc & 7;
      const float* src = &X[(size_t)(m0 + row) * NDIM + k0 + c * 8];
      rA[u][0] = *reinterpret_cast<const float4*>(src);
      rA[u][1] = *reinterpret_cast<const float4*>(src + 4);
    }
  };
  auto cvtWriteA = [&](int buf, int ts) {
    const int k0 = ts << 6;
    #pragma unroll
    for (int u = 0; u < 4; ++u) {
      const int bc = u * 256 + t;
      const int row = bc >> 3, c = bc & 7;
      bf16x8 o;
      o[0] = f2bf(rA[u][0].x); o[1] = f2bf(rA[u][0].y);
      o[2] = f2bf(rA[u][0].z); o[3] = f2bf(rA[u][0].w);
      o[4] = f2bf(rA[u][1].x); o[5] = f2bf(rA[u][1].y);
      o[6] = f2bf(rA[u][1].z); o[7] = f2bf(rA[u][1].w);
      *reinterpret_cast<bf16x8*>(
          (char*)&As[buf][0] + row * 128 + ((c ^ (row & 7)) << 4)) = o;
      *reinterpret_cast<bf16x8*>(&Xb[(size_t)(m0 + row) * NDIM + k0 + c * 8]) = o;
    }
  };

  auto compute = [&](int buf) {
    #pragma unroll
    for (int kk = 0; kk < 64; kk += 32) {
      bf16x8 a[4], b[4];
      #pragma unroll
      for (int i = 0; i < 4; ++i) {
        const int r = wr * 64 + i * 16 + lr;
        const int byte = r * 128 + ((((kk >> 3) + lg) ^ (lr & 7)) << 4);
        a[i] = *reinterpret_cast<const bf16x8*>((const char*)&As[buf][0] + byte);
      }
      #pragma unroll
      for (int j = 0; j < 4; ++j) {
        const int r = wc * 64 + j * 16 + lr;
        const int byte = r * 128 + ((((kk >> 3) + lg) ^ (lr & 7)) << 4);
        b[j] = *reinterpret_cast<const bf16x8*>((const char*)&Bs[buf][0] + byte);
      }
      #pragma unroll
      for (int i = 0; i < 4; ++i) {
        #pragma unroll
        for (int j = 0; j < 4; ++j)
          acc[i][j] = __builtin_amdgcn_mfma_f32_16x16x32_bf16(a[i], b[j], acc[i][j], 0, 0, 0);
      }
    }
  };

  issueA(0);
  cvtWriteA(0, 0);
  stageB(0, 0);
  issueA(1);
  asm volatile("s_waitcnt vmcnt(8)" ::: "memory");
  asm volatile("s_waitcnt lgkmcnt(0)" ::: "memory");
  __builtin_amdgcn_s_barrier();
  __builtin_amdgcn_sched_barrier(0);
  for (int ts = 0; ts < 7; ++ts) {
    cvtWriteA((ts + 1) & 1, ts + 1);
    stageB((ts + 1) & 1, ts + 1);
    if (ts < 6) issueA(ts + 2);
    asm volatile("s_waitcnt lgkmcnt(0)" ::: "memory");
    __builtin_amdgcn_s_barrier();
    compute(ts & 1);
    __builtin_amdgcn_s_barrier();
  }
  asm volatile("s_waitcnt vmcnt(0)" ::: "memory");
  __builtin_amdgcn_s_barrier();
  compute(1);
  __builtin_amdgcn_sched_barrier(0);

  const float l0 = lp2[0], l1 = lp2[1], l2 = lp2[2], l3 = lp2[3];
  const float lpv[4] = {l0, l1, l2, l3};

  float part[4][4];
  #pragma unroll
  for (int i = 0; i < 4; ++i)
    #pragma unroll
    for (int e = 0; e < 4; ++e) part[i][e] = 0.f;

  #pragma unroll
  for (int j = 0; j < 4; ++j) {
    const int Jg = c0 + wc * 64 + j * 16 + lr;
    #pragma unroll
    for (int e = 0; e < 4; ++e) {
      const float4 gw = gmm[e * NDIM + Jg];
      #pragma unroll
      for (int i = 0; i < 4; ++i) {
        const float kv = acc[i][j][e] + gw.w;
        const float d = kv - gw.x;
        part[i][e] += gw.y - d * d * gw.z;
      }
    }
  }
  #pragma unroll
  for (int off = 1; off < 16; off <<= 1) {
    #pragma unroll
    for (int i = 0; i < 4; ++i)
      #pragma unroll
      for (int e = 0; e < 4; ++e)
        part[i][e] += __shfl_xor(part[i][e], off, 64);
  }
  if (lr == 0) {
    const int h = wc;                        // ct = 0
    #pragma unroll
    for (int i = 0; i < 4; ++i) {
      #pragma unroll
      for (int e = 0; e < 4; ++e) {
        const int R = m0 + wr * 64 + i * 16 + 4 * lg + e;
        const int bn = R >> 2;
        const int bb = bn >> 11;
        const int nn = bn & (NN - 1);
        ll_ws[((size_t)((bb * NS + e) * NH + h)) * NN + nn] = part[i][e] + lpv[e];
      }
    }
  }
}

// ---------------------------------------------------------------------------
// kproj part 2 (gld_lds form, ct = 1..3): 3072 blocks. Heads 2-7.
// ---------------------------------------------------------------------------
__global__ __launch_bounds__(256) void kproj2_kernel(
    const short* __restrict__ Xb, const short* __restrict__ Wkb,
    const float4* __restrict__ gmm, const float* __restrict__ lp2,
    float* __restrict__ ll_ws)
{
  __shared__ short As[2][128 * 64];
  __shared__ short Bs[2][128 * 64];

  const int bid0 = blockIdx.x;
  const int xcd = bid0 & 7;
  const int q = bid0 >> 3;                 // 0..383
  const int mt = xcd * 128 + q / 3;
  const int ct = 1 + q % 3;                // 1..3
  const int m0 = mt * 128;
  const int c0 = ct * 128;

  const int t = threadIdx.x;
  const int l = t & 63;
  const int w = t >> 6;
  const int wr = w >> 1, wc = w & 1;
  const int lg = l >> 4, lr = l & 15;

  f32x4 acc[4][4] = {};

  const int g8 = (l & 7) ^ (l >> 3);
  const size_t gxa = (size_t)(m0 + w * 32 + (l >> 3)) * NDIM + g8 * 8;
  const size_t gba = (size_t)(c0 + w * 32 + (l >> 3)) * NDIM + g8 * 8;
  const int dA = (w * 32) * 64;

  auto stage = [&](int buf, int ts) {
    const int k0 = ts << 6;
    #pragma unroll
    for (int qq = 0; qq < 4; ++qq) {
      const size_t so = (size_t)(qq * 8) * NDIM + k0;
      const int dd = dA + (qq * 8) * 64;
      gld16(&Xb[gxa + so],  (char*)&As[buf][dd]);
      gld16(&Wkb[gba + so], (char*)&Bs[buf][dd]);
    }
  };

  auto compute = [&](int buf) {
    #pragma unroll
    for (int kk = 0; kk < 64; kk += 32) {
      bf16x8 a[4], b[4];
      #pragma unroll
      for (int i = 0; i < 4; ++i) {
        const int r = wr * 64 + i * 16 + lr;
        const int byte = r * 128 + ((((kk >> 3) + lg) ^ (lr & 7)) << 4);
        a[i] = *reinterpret_cast<const bf16x8*>((const char*)&As[buf][0] + byte);
      }
      #pragma unroll
      for (int j = 0; j < 4; ++j) {
        const int r = wc * 64 + j * 16 + lr;
        const int byte = r * 128 + ((((kk >> 3) + lg) ^ (lr & 7)) << 4);
        b[j] = *reinterpret_cast<const bf16x8*>((const char*)&Bs[buf][0] + byte);
      }
      #pragma unroll
      for (int i = 0; i < 4; ++i) {
        #pragma unroll
        for (int j = 0; j < 4; ++j)
          acc[i][j] = __builtin_amdgcn_mfma_f32_16x16x32_bf16(a[i], b[j], acc[i][j], 0, 0, 0);
      }
    }
  };

  stage(0, 0);
  __builtin_amdgcn_sched_barrier(0);
  for (int ts = 0; ts < 7; ++ts) {
    stage((ts + 1) & 1, ts + 1);
    asm volatile("s_waitcnt vmcnt(8)" ::: "memory");
    __builtin_amdgcn_s_barrier();
    compute(ts & 1);
    __builtin_amdgcn_s_barrier();
  }
  asm volatile("s_waitcnt vmcnt(0)" ::: "memory");
  __builtin_amdgcn_s_barrier();
  compute(1);
  __builtin_amdgcn_sched_barrier(0);

  const float l0 = lp2[0], l1 = lp2[1], l2 = lp2[2], l3 = lp2[3];
  const float lpv[4] = {l0, l1, l2, l3};

  float part[4][4];
  #pragma unroll
  for (int i = 0; i < 4; ++i)
    #pragma unroll
    for (int e = 0; e < 4; ++e) part[i][e] = 0.f;

  #pragma unroll
  for (int j = 0; j < 4; ++j) {
    const int Jg = c0 + wc * 64 + j * 16 + lr;
    #pragma unroll
    for (int e = 0; e < 4; ++e) {
      const float4 gw = gmm[e * NDIM + Jg];
      #pragma unroll
      for (int i = 0; i < 4; ++i) {
        const float kv = acc[i][j][e] + gw.w;
        const float d = kv - gw.x;
        part[i][e] += gw.y - d * d * gw.z;
      }
    }
  }
  #pragma unroll
  for (int off = 1; off < 16; off <<= 1) {
    #pragma unroll
    for (int i = 0; i < 4; ++i)
      #pragma unroll
      for (int e = 0; e < 4; ++e)
        part[i][e] += __shfl_xor(part[i][e], off, 64);
  }
  if (lr == 0) {
    const int h = ct * 2 + wc;               // heads 2..7
    #pragma unroll
    for (int i = 0; i < 4; ++i) {
      #pragma unroll
      for (int e = 0; e < 4; ++e) {
        const int R = m0 + wr * 64 + i * 16 + 4 * lg + e;
        const int bn = R >> 2;
        const int bb = bn >> 11;
        const int nn = bn & (NN - 1);
        ll_ws[((size_t)((bb * NS + e) * NH + h)) * NN + nn] = part[i][e] + lpv[e];
      }
    }
  }
}

// ---------------------------------------------------------------------------
// Y partials with per-chunk online-softmax stats (r15-proven form):
// block (bs, nq): per h, local max/sum over its 256 n's; Yp unnormalized.
// ---------------------------------------------------------------------------
__global__ __launch_bounds__(256) void y_kernel(
    const float* __restrict__ ll_ws, const short* __restrict__ Xb,
    float* __restrict__ Yp, float2* __restrict__ msws)
{
  __shared__ float wT[256][8];
  __shared__ float redm[8][4];
  __shared__ float reds[8][4];
  const int blk = blockIdx.x;
  const int bs = blk & 63;             // b*4+s
  const int nq = blk >> 6;             // 0..7
  const int b = bs >> 2, s = bs & 3;
  const int g0 = bs * 8;
  const int t = threadIdx.x;
  const int w = t >> 6, l = t & 63;

  float lv[8];
  #pragma unroll
  for (int h = 0; h < 8; ++h) {
    lv[h] = ll_ws[(size_t)(g0 + h) * NN + nq * 256 + t];
    float mm = lv[h];
    #pragma unroll
    for (int off = 1; off < 64; off <<= 1) mm = fmaxf(mm, __shfl_xor(mm, off, 64));
    if (l == 0) redm[h][w] = mm;
  }
  __syncthreads();
  float mx[8];
  #pragma unroll
  for (int h = 0; h < 8; ++h) {
    mx[h] = fmaxf(fmaxf(redm[h][0], redm[h][1]), fmaxf(redm[h][2], redm[h][3]));
    const float e = expf(lv[h] - mx[h]);
    wT[t][h] = e;
    float ss = e;
    #pragma unroll
    for (int off = 1; off < 64; off <<= 1) ss += __shfl_xor(ss, off, 64);
    if (l == 0) reds[h][w] = ss;
  }
  __syncthreads();
  if (t < 8) {
    const float sum = reds[t][0] + reds[t][1] + reds[t][2] + reds[t][3];
    msws[(size_t)(g0 + t) * 8 + nq] = make_float2(mx[t], sum);
  }

  const ushort2* X2 = reinterpret_cast<const ushort2*>(Xb);
  const size_t xbase = ((size_t)(b * 2048 + nq * 256) * 4 + s) * 256 + t;
  float acc[8][2] = {};
  #pragma unroll 4
  for (int n = 0; n < 256; ++n) {
    const ushort2 xv = X2[xbase + (size_t)n * 1024];
    const float x0 = bf2f((short)xv.x), x1 = bf2f((short)xv.y);
    const float4 w0 = *reinterpret_cast<const float4*>(&wT[n][0]);
    const float4 w1 = *reinterpret_cast<const float4*>(&wT[n][4]);
    acc[0][0] += w0.x * x0; acc[0][1] += w0.x * x1;
    acc[1][0] += w0.y * x0; acc[1][1] += w0.y * x1;
    acc[2][0] += w0.z * x0; acc[2][1] += w0.z * x1;
    acc[3][0] += w0.w * x0; acc[3][1] += w0.w * x1;
    acc[4][0] += w1.x * x0; acc[4][1] += w1.x * x1;
    acc[5][0] += w1.y * x0; acc[5][1] += w1.y * x1;
    acc[6][0] += w1.z * x0; acc[6][1] += w1.z * x1;
    acc[7][0] += w1.w * x0; acc[7][1] += w1.w * x1;
  }
  #pragma unroll
  for (int h = 0; h < 8; ++h) {
    float* yp = Yp + ((size_t)((nq * 64 + bs) * 8 + h)) * 512 + 2 * t;
    yp[0] = acc[h][0]; yp[1] = acc[h][1];
  }
}

// ---------------------------------------------------------------------------
// Pool-project with online-softmax merge.
// ---------------------------------------------------------------------------
__global__ __launch_bounds__(256) void poolproj_kernel(
    const float* __restrict__ Yp, const float2* __restrict__ msws,
    const float* __restrict__ WvT, const float* __restrict__ bvp,
    const float* __restrict__ Mp, float* __restrict__ O0)
{
  __shared__ float ys[512];
  __shared__ float pr[4][64];
  const int g = blockIdx.x;            // (b*4+s)*8+h
  const int bs = g >> 3, h = g & 7;
  const int s = bs & 3;
  const int t = threadIdx.x;

  const float2* msp = msws + (size_t)g * 8;
  float M = -1e30f;
  #pragma unroll
  for (int q = 0; q < 8; ++q) M = fmaxf(M, msp[q].x);
  float cq[8];
  float S = 0.f;
  #pragma unroll
  for (int q = 0; q < 8; ++q) {
    cq[q] = expf(msp[q].x - M);
    S += msp[q].y * cq[q];
  }
  const float rS = 1.f / S;

  float a0 = 0.f, a1 = 0.f;
  #pragma unroll
  for (int q = 0; q < 8; ++q) {
    const float* yp = Yp + ((size_t)((q * 64 + bs) * 8 + h)) * 512;
    const float c = cq[q] * rS;
    a0 += yp[t] * c;
    a1 += yp[t + 256] * c;
  }
  ys[t] = a0; ys[t + 256] = a1;
  __syncthreads();

  const int d = t & 63, p = t >> 6;
  const float* wt = WvT + ((size_t)h * 512 + p * 128) * 64 + d;
  const float* yy = ys + p * 128;
  float acc = 0.f;
  #pragma unroll 4
  for (int i = 0; i < 128; ++i) acc += yy[i] * wt[(size_t)i * 64];
  pr[p][d] = acc;
  __syncthreads();
  if (t < 64) {
    const float tot = pr[0][t] + pr[1][t] + pr[2][t] + pr[3][t];
    O0[(size_t)g * 64 + t] = Mp[s * NDIM + h * NDS + t] + bvp[h * 64 + t] + tot;
  }
}

// ---------------------------------------------------------------------------
// Fused BN1 + MLP.
// ---------------------------------------------------------------------------
__global__ __launch_bounds__(256) void bnmlp_kernel(
    const float* __restrict__ O0, const float* __restrict__ gg,
    const float* __restrict__ bb, const float* __restrict__ Wo,
    const float* __restrict__ bo, float* __restrict__ Zo)
{
  __shared__ float ys[512];
  const int blk = blockIdx.x;
  const int t = threadIdx.x;
  const int r = blk >> 1;              // row 0..63 (b*4+s)
  const int b = r >> 2, s = r & 3;

  #pragma unroll
  for (int u = 0; u < 2; ++u) {
    const int i = u * 256 + t;
    const int f = s * 512 + i;
    float x[NB];
    float m = 0.f;
    #pragma unroll
    for (int bq = 0; bq < NB; ++bq) { x[bq] = O0[bq * 2048 + f]; m += x[bq]; }
    m *= (1.f / NB);
    float v = 0.f;
    #pragma unroll
    for (int bq = 0; bq < NB; ++bq) { const float d = x[bq] - m; v += d * d; }
    v *= (1.f / NB);
    const float inv = rsqrtf(v + 1e-5f) * gg[f];
    ys[i] = (x[b] - m) * inv + bb[f];
  }
  __syncthreads();

  const int j = ((blk & 1) << 8) + t;
  const float4* yv = reinterpret_cast<const float4*>(ys);
  const float4* wrow = reinterpret_cast<const float4*>(Wo + (size_t)j * NDIM);
  float acc = 0.f;
  #pragma unroll 4
  for (int i = 0; i < 128; ++i) {
    const float4 a = yv[i], w = wrow[i];
    acc += a.x * w.x + a.y * w.y + a.z * w.z + a.w * w.w;
  }
  Zo[(size_t)r * 512 + j] = ys[j] + fmaxf(acc + bo[j], 0.f);
}

// ---------------------------------------------------------------------------
// Final BatchNorm1d (training mode, biased var, eps=1e-5) over B=16.
// ---------------------------------------------------------------------------
__global__ __launch_bounds__(256) void bn_kernel(
    const float* __restrict__ Xin, const float* __restrict__ gg,
    const float* __restrict__ bb, float* __restrict__ Yo)
{
  const int f = blockIdx.x * 256 + threadIdx.x;  // 0..2047
  float x[NB];
  float m = 0.f;
  #pragma unroll
  for (int b = 0; b < NB; ++b) { x[b] = Xin[b * (NS * NDIM) + f]; m += x[b]; }
  m *= (1.f / NB);
  float v = 0.f;
  #pragma unroll
  for (int b = 0; b < NB; ++b) { const float d = x[b] - m; v += d * d; }
  v *= (1.f / NB);
  const float inv = rsqrtf(v + 1e-5f) * gg[f];
  const float bf = bb[f];
  #pragma unroll
  for (int b = 0; b < NB; ++b) Yo[b * (NS * NDIM) + f] = (x[b] - m) * inv + bf;
}

extern "C" void kernel_launch(void* const* d_in, const int* in_sizes, int n_in,
                              void* d_out, int out_size, void* d_ws, size_t ws_size,
                              hipStream_t stream) {
  (void)in_sizes; (void)n_in; (void)out_size; (void)ws_size;
  const float* X  = (const float*)d_in[0];
  const float* M  = (const float*)d_in[1];
  const float* S  = (const float*)d_in[2];
  const float* p  = (const float*)d_in[3];
  const float* Wk = (const float*)d_in[4];
  const float* bk = (const float*)d_in[5];
  const float* Wv = (const float*)d_in[6];
  const float* bv = (const float*)d_in[7];
  const float* Wo = (const float*)d_in[8];
  const float* bo = (const float*)d_in[9];
  const float* g0 = (const float*)d_in[10];
  const float* b0 = (const float*)d_in[11];
  const float* g1 = (const float*)d_in[12];
  const float* b1 = (const float*)d_in[13];

  char* ws = (char*)d_ws;
  short* Xb    = (short*)ws;                                    // 128 MiB bf16 X
  float* ll_ws = (float*)(ws + (size_t)134217728);              // 4 MiB logits
  float* Yp    = (float*)(ws + (size_t)138416128);              // 8 MiB partials
  float* O0    = (float*)(ws + (size_t)146804736);              // 128 KiB
  float* Z     = (float*)(ws + (size_t)147066880);              // 128 KiB
  short* Wkb   = (short*)(ws + (size_t)147197952);              // 512 KiB
  float* WvT   = (float*)(ws + (size_t)147722240);              // 1 MiB
  float4* gmm  = (float4*)(ws + (size_t)148770816);             // 32 KiB
  float* lp2   = (float*)(ws + (size_t)148803584);              // 16 B
  float2* msws = (float2*)(ws + (size_t)148803712);             // 32 KiB

  prep_kernel<<<1160, 256, 0, stream>>>(Wv, WvT, Wk, Wkb, M, S, p, bk, gmm, lp2);
  kproj1_kernel<<<1024, 256, 0, stream>>>(X, Wkb, gmm, lp2, ll_ws, Xb);
  kproj2_kernel<<<3072, 256, 0, stream>>>(Xb, Wkb, gmm, lp2, ll_ws);
  y_kernel<<<512, 256, 0, stream>>>(ll_ws, Xb, Yp, msws);
  poolproj_kernel<<<512, 256, 0, stream>>>(Yp, msws, WvT, bv, M, O0);
  bnmlp_kernel<<<128, 256, 0, stream>>>(O0, g0, b0, Wo, bo, Z);
  bn_kernel<<<8, 256, 0, stream>>>(Z, g1, b1, (float*)d_out);
}